// Round 5
// baseline (254.696 us; speedup 1.0000x reference)
//
#include <hip/hip_runtime.h>

#define B_ 16
#define C_ 3
#define H_ 384
#define W_ 1280
#define HW_ (H_*W_)
#define EPS_ 1e-7f
#define QB_ 960   // 512-px blocks per batch image (HW_/512)

typedef float v2f __attribute__((ext_vector_type(2)));

// single global_load_dwordx2 (4B-aligned 8B load; x-pair shares a line 15/16)
__device__ __forceinline__ v2f load2(const float* p) {
  v2f r;
  __builtin_memcpy(&r, p, 8);
  return r;
}

__device__ __forceinline__ void mat3mul(const float* A, const float* Bm, float* C) {
  #pragma unroll
  for (int i = 0; i < 3; i++)
    #pragma unroll
    for (int j = 0; j < 3; j++)
      C[i*3+j] = A[i*3+0]*Bm[0*3+j] + A[i*3+1]*Bm[1*3+j] + A[i*3+2]*Bm[2*3+j];
}

// M = K * R * inv(K), T = K * t for batch b.
__device__ void compute_MT(const float* __restrict__ pose,
                           const float* __restrict__ intr,
                           int b, float* M, float* T)
{
  float K[9];
  #pragma unroll
  for (int i = 0; i < 9; i++) K[i] = intr[b*9 + i];
  float aa0 = pose[b*6 + 0], aa1 = pose[b*6 + 1], aa2 = pose[b*6 + 2];
  float t0  = pose[b*6 + 3], t1  = pose[b*6 + 4], t2  = pose[b*6 + 5];

  float theta = sqrtf(aa0*aa0 + aa1*aa1 + aa2*aa2);
  float invn  = 1.0f / (theta + EPS_);
  float x = aa0*invn, y = aa1*invn, z = aa2*invn;
  float c = cosf(theta), s = sinf(theta), t = 1.0f - c;
  float R[9] = {
    t*x*x + c,   t*x*y - s*z, t*z*x + s*y,
    t*x*y + s*z, t*y*y + c,   t*y*z - s*x,
    t*z*x - s*y, t*y*z + s*x, t*z*z + c
  };

  float a = K[0], bb = K[1], cc = K[2];
  float d = K[3], e  = K[4], f  = K[5];
  float g = K[6], h  = K[7], ii = K[8];
  float A0 = e*ii - f*h, A1 = f*g - d*ii, A2 = d*h - e*g;
  float id = 1.0f / (a*A0 + bb*A1 + cc*A2);
  float iK[9] = {
    A0*id, (cc*h - bb*ii)*id, (bb*f - cc*e)*id,
    A1*id, (a*ii - cc*g)*id,  (cc*d - a*f)*id,
    A2*id, (bb*g - a*h)*id,   (a*e  - bb*d)*id
  };

  float KR[9];
  mat3mul(K, R, KR);
  mat3mul(KR, iK, M);
  T[0] = K[0]*t0 + K[1]*t1 + K[2]*t2;
  T[1] = K[3]*t0 + K[4]*t1 + K[5]*t2;
  T[2] = K[6]*t0 + K[7]*t1 + K[8]*t2;
}

struct Tap { int rb0, rb1; float wax, way, wbx, wby; };

__device__ __forceinline__ Tap make_tap(
    int p, float d,
    float m00, float m01, float m02,
    float m10, float m11, float m12,
    float m20, float m21, float m22,
    float T0, float T1, float T2)
{
  int j = p % W_;
  int i = p / W_;
  float xf = (float)j, yf = (float)i;

  float cx = (m00*xf + m01*yf + m02)*d + T0;
  float cy = (m10*xf + m11*yf + m12)*d + T1;
  float cz = (m20*xf + m21*yf + m22)*d + T2;
  float inv = 1.0f / (cz + EPS_);
  float px = cx * inv;
  float py = cy * inv;

  float x0f = floorf(px), y0f = floorf(py);
  float x1f = x0f + 1.0f, y1f = y0f + 1.0f;
  float wx1 = px - x0f, wx0 = 1.0f - wx1;
  float wy1 = py - y0f, wy0 = 1.0f - wy1;

  float mx0 = (x0f >= 0.0f && x0f <= (float)(W_-1)) ? 1.0f : 0.0f;
  float mx1 = (x1f >= 0.0f && x1f <= (float)(W_-1)) ? 1.0f : 0.0f;
  float my0 = (y0f >= 0.0f && y0f <= (float)(H_-1)) ? 1.0f : 0.0f;
  float my1 = (y1f >= 0.0f && y1f <= (float)(H_-1)) ? 1.0f : 0.0f;

  int xc0 = (int)fminf(fmaxf(x0f, 0.0f), (float)(W_-1));
  int xc1 = (int)fminf(fmaxf(x1f, 0.0f), (float)(W_-1));
  int yc0 = (int)fminf(fmaxf(y0f, 0.0f), (float)(H_-1));
  int yc1 = (int)fminf(fmaxf(y1f, 0.0f), (float)(H_-1));

  float w00 = wx0*wy0*mx0*my0;
  float w01 = wx1*wy0*mx1*my0;
  float w10 = wx0*wy1*mx0*my1;
  float w11 = wx1*wy1*mx1*my1;

  // x-pair merge (exact under all clamp cases, see R3 derivation)
  int base = xc0 < (W_-2) ? xc0 : (W_-2);
  bool s0 = (xc0 == base);
  bool s1 = (xc1 == base + 1);

  Tap t;
  t.wax = (s0 ? w00 : 0.0f) + (s1 ? 0.0f : w01);
  t.way = (s0 ? 0.0f : w00) + (s1 ? w01 : 0.0f);
  t.wbx = (s0 ? w10 : 0.0f) + (s1 ? 0.0f : w11);
  t.wby = (s0 ? 0.0f : w10) + (s1 ? w11 : 0.0f);
  t.rb0 = yc0*W_ + base;
  t.rb1 = yc1*W_ + base;
  return t;
}

// XCD-banded grid: blockIdx.x % 8 (the presumed XCD round-robin class) is
// pinned to 2 of the 16 batches, swept in row-major order -> per-XCD L2
// working set is a few src rows, not 16 batches' worth.
__global__ __launch_bounds__(256) void warp_kernel(
    const float* __restrict__ src,
    const float* __restrict__ depth,
    const float* __restrict__ pose,
    const float* __restrict__ intr,
    float* __restrict__ out)
{
  __shared__ float sp[12];
  int n   = blockIdx.x;
  int xcd = n & 7;
  int s   = n >> 3;            // [0, 2*QB_)
  int bo  = (s >= QB_) ? 1 : 0;
  int q   = s - bo * QB_;      // [0, QB_)
  int b   = (xcd << 1) | bo;   // 2 batches per XCD class

  if (threadIdx.x == 0) {
    float M[9], T[3];
    compute_MT(pose, intr, b, M, T);
    #pragma unroll
    for (int i = 0; i < 9; i++) sp[i] = M[i];
    #pragma unroll
    for (int i = 0; i < 3; i++) sp[9 + i] = T[i];
  }
  __syncthreads();
  float m00 = sp[0], m01 = sp[1], m02 = sp[2];
  float m10 = sp[3], m11 = sp[4], m12 = sp[5];
  float m20 = sp[6], m21 = sp[7], m22 = sp[8];
  float T0  = sp[9], T1  = sp[10], T2 = sp[11];

  // two pixels per thread -> 12 outstanding gathers (2x MLP)
  int p0 = q * 512 + threadIdx.x;
  int p1 = p0 + 256;

  size_t db = (size_t)b * HW_;
  float d0 = depth[db + p0];
  float d1 = depth[db + p1];

  Tap A = make_tap(p0, d0, m00,m01,m02, m10,m11,m12, m20,m21,m22, T0,T1,T2);
  Tap Bt= make_tap(p1, d1, m00,m01,m02, m10,m11,m12, m20,m21,m22, T0,T1,T2);

  size_t sb = (size_t)b * C_ * HW_;
  const float* c0 = src + sb;
  const float* c1 = c0 + HW_;
  const float* c2 = c1 + HW_;

  v2f A00 = load2(c0 + A.rb0),  A01 = load2(c0 + A.rb1);
  v2f A10 = load2(c1 + A.rb0),  A11 = load2(c1 + A.rb1);
  v2f A20 = load2(c2 + A.rb0),  A21 = load2(c2 + A.rb1);
  v2f B00 = load2(c0 + Bt.rb0), B01 = load2(c0 + Bt.rb1);
  v2f B10 = load2(c1 + Bt.rb0), B11 = load2(c1 + Bt.rb1);
  v2f B20 = load2(c2 + Bt.rb0), B21 = load2(c2 + Bt.rb1);

  float vA0 = A00.x*A.wax + A00.y*A.way + A01.x*A.wbx + A01.y*A.wby;
  float vA1 = A10.x*A.wax + A10.y*A.way + A11.x*A.wbx + A11.y*A.wby;
  float vA2 = A20.x*A.wax + A20.y*A.way + A21.x*A.wbx + A21.y*A.wby;
  float vB0 = B00.x*Bt.wax + B00.y*Bt.way + B01.x*Bt.wbx + B01.y*Bt.wby;
  float vB1 = B10.x*Bt.wax + B10.y*Bt.way + B11.x*Bt.wbx + B11.y*Bt.wby;
  float vB2 = B20.x*Bt.wax + B20.y*Bt.way + B21.x*Bt.wbx + B21.y*Bt.wby;

  __builtin_nontemporal_store(vA0, &out[sb + p0]);
  __builtin_nontemporal_store(vA1, &out[sb + HW_ + p0]);
  __builtin_nontemporal_store(vA2, &out[sb + 2*(size_t)HW_ + p0]);
  __builtin_nontemporal_store(vB0, &out[sb + p1]);
  __builtin_nontemporal_store(vB1, &out[sb + HW_ + p1]);
  __builtin_nontemporal_store(vB2, &out[sb + 2*(size_t)HW_ + p1]);
}

extern "C" void kernel_launch(void* const* d_in, const int* in_sizes, int n_in,
                              void* d_out, int out_size, void* d_ws, size_t ws_size,
                              hipStream_t stream) {
  const float* src   = (const float*)d_in[0];
  const float* depth = (const float*)d_in[1];
  const float* pose  = (const float*)d_in[2];
  const float* intr  = (const float*)d_in[3];
  float* out = (float*)d_out;

  warp_kernel<<<dim3(8 * 2 * QB_), 256, 0, stream>>>(src, depth, pose, intr, out);
}